// Round 11
// baseline (1197.738 us; speedup 1.0000x reference)
//
#include <hip/hip_runtime.h>

// Quantized MSA, all-MFMA (f16 exact fixed-point digits).
// R15: qkv/out gload_lds + swizzle — WIN (186.4 -> 180.0). R16/17: direct-
//   global attn — REGRESSION. R18: qkv 2-phase — REGRESSION. R19: out 32x32
//   clone — NEUTRAL. R20: qkv 128^2 — REGRESSION (occupancy). R21: qkv 144B
//   rows div-9 — NEUTRAL (kept). R22: out 64x64 — NEUTRAL (kept); residency
//   model for out falsified: out was never large.
// R23: attention TLP doubled IN-PLACE: 8 waves (4 m-strips x 2 q-halves) x
//   KVBLK=128, 16 iters. Same total MFMA+VALU; waves/CU 12 -> 24 (grid was
//   the occupancy cap: 768 blk = 3/CU, VGPR 76 allows 6 waves/SIMD). LDS
//   single-buffer Ks[128x72]+Vs[64x136] = 35.8KB (dbuf was neutral, R14).
//   Sigma is within-32-block => phase2 local-B trick unchanged for wi in 0..3.
//   Epilogue: pair-merge (0,2),(1,3) via LDS, then old 2-wave exchange.
//   qkv (R21) / out (R22) / prep byte-identical.

#define NTOK 4096      // B*N
#define DIM  768
#define NH   12
#define DH   64
#define SEQ  2048
#define QKVD 2304      // 3*DIM
#define NBH  24        // B*NH
#define LSTR 72        // f16 LDS row stride: 144 B rows (16B-aligned)
#define KSTR 72        // attention K tile row stride
#define VSTR 136       // attention V^T tile row stride (128 + 8 pad)

typedef _Float16 half8 __attribute__((ext_vector_type(8)));
typedef _Float16 half4 __attribute__((ext_vector_type(4)));
typedef __fp16   fp16x2 __attribute__((ext_vector_type(2)));
typedef float floatx4 __attribute__((ext_vector_type(4)));
typedef float floatx16 __attribute__((ext_vector_type(16)));

// direct global->LDS DMA, 16B/lane; dest = wave-uniform base + lane*16
#define GLOAD16(gsrc, ldst) \
    __builtin_amdgcn_global_load_lds( \
        (const __attribute__((address_space(1))) void*)(gsrc), \
        (__attribute__((address_space(3))) void*)(ldst), 16, 0, 0)

// ---------------- K0: merged prep (X digit split + weight/bias quant) --------
__global__ __launch_bounds__(256) void prep(
    const float* __restrict__ X,
    const float* __restrict__ wqkv, const float* __restrict__ bqkv,
    const float* __restrict__ wp,   const float* __restrict__ bp,
    _Float16* __restrict__ Xh, _Float16* __restrict__ Xl,
    _Float16* __restrict__ W16, _Float16* __restrict__ Wp16,
    float* __restrict__ bq24, float* __restrict__ bp16)
{
    int i = blockIdx.x * 256 + threadIdx.x;
    int i4 = i * 4;
    if (i4 < NTOK * DIM) {           // X (32,16): clamp unreachable for N(0,1)
        float4 x = *(const float4*)(X + i4);
        float xi[4] = {x.x, x.y, x.z, x.w};
        half4 oh, ol;
#pragma unroll
        for (int j = 0; j < 4; ++j) {
            float v = rintf(xi[j] * 65536.0f);
            float h = rintf(v * (1.0f / 2048.0f));
            ((_Float16*)&oh)[j] = (_Float16)h;
            ((_Float16*)&ol)[j] = (_Float16)(v - 2048.0f * h);
        }
        *(half4*)(Xh + i4) = oh;
        *(half4*)(Xl + i4) = ol;
    }
    if (i4 < QKVD * DIM) {           // w*0.05: |w_int| <~ 70, clamp unreachable
        float4 w = *(const float4*)(wqkv + i4);
        half4 o = {(_Float16)rintf(w.x * 256.0f), (_Float16)rintf(w.y * 256.0f),
                   (_Float16)rintf(w.z * 256.0f), (_Float16)rintf(w.w * 256.0f)};
        *(half4*)(W16 + i4) = o;
    }
    if (i4 < DIM * DIM) {
        float4 w = *(const float4*)(wp + i4);
        half4 o = {(_Float16)rintf(w.x * 256.0f), (_Float16)rintf(w.y * 256.0f),
                   (_Float16)rintf(w.z * 256.0f), (_Float16)rintf(w.w * 256.0f)};
        *(half4*)(Wp16 + i4) = o;
    }
    if (i < QKVD) bq24[i] = rintf(bqkv[i] * 256.0f) * 65536.0f;  // int24 units
    if (i < DIM)  bp16[i] = rintf(bp[i] * 256.0f) * 256.0f;      // int16 units
}

// ---------------- K1: QKV projection, 32x32 MFMA, 64x128 tile, 4 blk/CU ------
// 144B LDS rows + gload_lds staging via div-9 slot mapping; conflict-free reads.
__global__ __launch_bounds__(256, 4) void qkv_mfma(
    const _Float16* __restrict__ Xh, const _Float16* __restrict__ Xl,
    const _Float16* __restrict__ W16, const float* __restrict__ bq24,
    _Float16* __restrict__ Q16, _Float16* __restrict__ K16,
    _Float16* __restrict__ Vt16)
{
    __shared__ __align__(16) _Float16 Ah[64 * LSTR];    //  9216 B
    __shared__ __align__(16) _Float16 Al[64 * LSTR];    //  9216 B
    __shared__ __align__(16) _Float16 Bs[128 * LSTR];   // 18432 B
    const int t = threadIdx.x;
    const int w = t >> 6, lane = t & 63;
    const int l31 = lane & 31, hi = lane >> 5;
    const int wr = w >> 1;                // row strip (0/1)
    const int wc = w & 1;                 // col half (0/1)
    const int m0 = blockIdx.x * 64;       // token rows (x-fastest: XCD = x%8)
    const int col0 = blockIdx.y * 128;    // output cols

    // staging: wave p stages plane p. Slot s = 64j + lane covers LDS bytes
    // s*16; row = s/9, slot-in-row = s%9 (9th slot = 8-half pad, refetch g0).
    const _Float16* gsrc0 = (w == 0) ? Xh + (size_t)m0 * DIM
                          : (w == 1) ? Xl + (size_t)m0 * DIM
                          : W16 + (size_t)(col0 + ((w == 3) ? 64 : 0)) * DIM;
    _Float16* ldst0 = (w == 0) ? Ah : (w == 1) ? Al
                      : Bs + ((w == 3) ? 64 * LSTR : 0);
    int goff[9];                          // per-lane source elem offsets
#pragma unroll
    for (int j = 0; j < 9; ++j) {
        int s = 64 * j + lane;            // 0..575
        int row = (s * 7282) >> 16;       // exact s/9 for s < 32768
        int sl = s - 9 * row;             // 0..8
        goff[j] = row * DIM + ((sl & 7) * 8);   // sl==8 -> granule 0 (pad)
    }

    floatx16 acch[2], accl[2];            // [ct] -- constant indices after unroll
#pragma unroll
    for (int ct = 0; ct < 2; ++ct)
#pragma unroll
        for (int r = 0; r < 16; ++r) { acch[ct][r] = 0.f; accl[ct][r] = 0.f; }

    for (int k0 = 0; k0 < DIM; k0 += 64) {
        __syncthreads();
#pragma unroll
        for (int j = 0; j < 9; ++j)
            GLOAD16(gsrc0 + k0 + goff[j], ldst0 + j * 512);
        __syncthreads();
#pragma unroll
        for (int i = 0; i < 4; ++i) {     // k-step of 16
            const int arow = 32 * wr + l31;
            half8 ah = *(const half8*)(&Ah[arow * LSTR + 16 * i + 8 * hi]);
            half8 al = *(const half8*)(&Al[arow * LSTR + 16 * i + 8 * hi]);
#pragma unroll
            for (int ct = 0; ct < 2; ++ct) {
                const int brow = 64 * wc + 32 * ct + l31;
                half8 bf = *(const half8*)(&Bs[brow * LSTR + 16 * i + 8 * hi]);
                acch[ct] = __builtin_amdgcn_mfma_f32_32x32x16_f16(ah, bf, acch[ct], 0, 0, 0);
                accl[ct] = __builtin_amdgcn_mfma_f32_32x32x16_f16(al, bf, accl[ct], 0, 0, 0);
            }
        }
    }

    // epilogue: C rows = token-rel er = (r&3)+8*(r>>2)+4*hi, cols = c-rel l31.
    const int b_ = m0 >> 11;
    const int nbase = (m0 & 2047) + 32 * wr;
#pragma unroll
    for (int ct = 0; ct < 2; ++ct) {
        const int c = col0 + 64 * wc + 32 * ct + l31;
        const int h = c / 192;
        const int jj = c % 192;
        const int kind = jj >> 6;         // 0=Q, 1=K, 2=V (uniform per ct-tile)
        const int e = jj & 63;
        const int bh = b_ * NH + h;
        const float bb = bq24[c];
        float qv[16];
#pragma unroll
        for (int r = 0; r < 16; ++r) {
            float y = fmaf(2048.0f, acch[ct][r], accl[ct][r]) + bb;
            float q = rintf(y * (1.0f / 65536.0f));
            qv[r] = fminf(fmaxf(q, -32768.0f), 32767.0f);
        }
        if (kind == 2) {
            // sigma (swap bit2<->bit3 within 16-block): er = 8g'+4hi+j maps to
            // 16*(g>>1) + 8*hi + 4*(g&1) + j -- j consecutive -> half4 stores.
#pragma unroll
            for (int g = 0; g < 4; ++g) {
                int nv = nbase + 16 * (g >> 1) + 8 * hi + 4 * (g & 1);
                half4 o = {(_Float16)qv[4 * g + 0], (_Float16)qv[4 * g + 1],
                           (_Float16)qv[4 * g + 2], (_Float16)qv[4 * g + 3]};
                *(half4*)(Vt16 + ((size_t)bh * DH + e) * SEQ + nv) = o;
            }
        } else {
            _Float16* dst = (kind == 0) ? Q16 : K16;
#pragma unroll
            for (int r = 0; r < 16; ++r) {
                int er = (r & 3) + 8 * (r >> 2) + 4 * hi;
                dst[((size_t)bh * SEQ + nbase + er) * DH + e] = (_Float16)qv[r];
            }
        }
    }
}

// ---------------- K2: attention, 32x32 MFMA, 8 waves x KVBLK=128 ------------
// 4 m-strips (wi) x 2 q-halves (wj); 16 iters; single-buffered K/V staging.
__global__ __launch_bounds__(512, 6) void attention_mfma(
    const _Float16* __restrict__ Q16, const _Float16* __restrict__ K16,
    const _Float16* __restrict__ Vt16,
    _Float16* __restrict__ Zh16, _Float16* __restrict__ Zl16)
{
    // Ks[128][72] (18432 B) + Vs[64][136] (17408 B) = 35840 B.
    // Epilogue scratch overlays: pair-merge 33792 B, exchange 16896 B.
    __shared__ __align__(16) char smem[128 * KSTR * 2 + 64 * VSTR * 2];
    _Float16* Ks = (_Float16*)smem;
    _Float16* Vs = Ks + 128 * KSTR;
    float* scr = (float*)smem;

    const int t = threadIdx.x;
    const int bh = blockIdx.x;
    const int qt = blockIdx.y;
    const int w = t >> 6, lane = t & 63;
    const int l31 = lane & 31, hi = lane >> 5;
    const int wj = w & 1;        // q-half
    const int wi = w >> 1;       // m-strip 0..3
    const _Float16* Qg = Q16 + ((size_t)bh * SEQ + qt * 64) * DH;
    const _Float16* Kg = K16 + (size_t)bh * SEQ * DH;
    const _Float16* Vg = Vt16 + (size_t)bh * DH * SEQ;

    // staging slots: 512 threads x 2 slots cover K(128x8 gran) + V(64x16 gran)
    const int sB = t + 512;
    const int kr0 = t >> 3,  kk0 = t & 7;
    const int kr1 = sB >> 3, kk1 = sB & 7;
    const int vr0 = t >> 4,  vm0 = t & 15;
    const int vr1 = sB >> 4, vm1 = sB & 15;

    // Q B-frags (whole kernel): B[n=q=l31][k_e = 16i + 8hi + j]
    half8 qf[4];
#pragma unroll
    for (int i = 0; i < 4; ++i)
        qf[i] = *(const half8*)(Qg + (32 * wj + l31) * DH + 16 * i + 8 * hi);

    // prologue: load tile 0 into regs
    half8 pk0 = *(const half8*)(Kg + (size_t)kr0 * DH + kk0 * 8);
    half8 pk1 = *(const half8*)(Kg + (size_t)kr1 * DH + kk1 * 8);
    half8 pv0 = *(const half8*)(Vg + (size_t)vr0 * SEQ + vm0 * 8);
    half8 pv1 = *(const half8*)(Vg + (size_t)vr1 * SEQ + vm1 * 8);

    floatx16 acc0h, acc0l, acc1h, acc1l;   // [et=0/1][digit h/l]
#pragma unroll
    for (int r = 0; r < 16; ++r) { acc0h[r] = 0.f; acc0l[r] = 0.f; acc1h[r] = 0.f; acc1l[r] = 0.f; }

    for (int it = 0; it < 16; ++it) {
        __syncthreads();                   // prior tile's reads complete
        *(half8*)(&Ks[kr0 * KSTR + kk0 * 8]) = pk0;
        *(half8*)(&Ks[kr1 * KSTR + kk1 * 8]) = pk1;
        *(half8*)(&Vs[vr0 * VSTR + vm0 * 8]) = pv0;
        *(half8*)(&Vs[vr1 * VSTR + vm1 * 8]) = pv1;
        __syncthreads();                   // writes visible

        // T14: issue next tile's loads; latency hides under this tile's compute
        if (it < 15) {
            const int mn = (it + 1) * 128;
            pk0 = *(const half8*)(Kg + (size_t)(mn + kr0) * DH + kk0 * 8);
            pk1 = *(const half8*)(Kg + (size_t)(mn + kr1) * DH + kk1 * 8);
            pv0 = *(const half8*)(Vg + (size_t)vr0 * SEQ + mn + vm0 * 8);
            pv1 = *(const half8*)(Vg + (size_t)vr1 * SEQ + mn + vm1 * 8);
        }

        // phase 1: S strip = K(strip wi) . Q^T ; sacc = S_raw * 65536
        floatx16 sc;
#pragma unroll
        for (int r = 0; r < 16; ++r) sc[r] = 0.f;
        __builtin_amdgcn_s_setprio(1);
#pragma unroll
        for (int i = 0; i < 4; ++i) {
            half8 kf = *(const half8*)(&Ks[(32 * wi + l31) * KSTR + 16 * i + 8 * hi]);
            sc = __builtin_amdgcn_mfma_f32_32x32x16_f16(kf, qf[i], sc, 0, 0, 0);
        }
        __builtin_amdgcn_s_setprio(0);

        // quantize (16,8) + digit split in registers
        float hh[16], ll[16];
#pragma unroll
        for (int r = 0; r < 16; ++r) {
            float v = rintf(sc[r] * 0.00390625f);
            v = fminf(fmaxf(v, -32768.0f), 32767.0f);
            float h = rintf(v * (1.0f / 2048.0f));
            hh[r] = h;
            ll[r] = fmaf(-2048.0f, h, v);
        }
        int dwh[4][2], dwl[4][2];
        union { fp16x2 h; int i; } cv;
#pragma unroll
        for (int g = 0; g < 4; ++g) {
            cv.h = __builtin_amdgcn_cvt_pkrtz(hh[4 * g + 0], hh[4 * g + 1]); dwh[g][0] = cv.i;
            cv.h = __builtin_amdgcn_cvt_pkrtz(hh[4 * g + 2], hh[4 * g + 3]); dwh[g][1] = cv.i;
            cv.h = __builtin_amdgcn_cvt_pkrtz(ll[4 * g + 0], ll[4 * g + 1]); dwl[g][0] = cv.i;
            cv.h = __builtin_amdgcn_cvt_pkrtz(ll[4 * g + 2], ll[4 * g + 3]); dwl[g][1] = cv.i;
        }

        // phase 2: A = V^T rows (sigma-ordered cols of strip wi), B = local S.
        half8 vf[2][2];
#pragma unroll
        for (int et = 0; et < 2; ++et)
#pragma unroll
            for (int c = 0; c < 2; ++c)
                vf[et][c] = *(const half8*)(&Vs[(32 * et + l31) * VSTR + 32 * wi + 16 * c + 8 * hi]);
        __builtin_amdgcn_s_setprio(1);
#pragma unroll
        for (int c = 0; c < 2; ++c) {
            union { int b[4]; half8 v; } ubh, ubl;
            ubh.b[0] = dwh[2 * c][0];     ubh.b[1] = dwh[2 * c][1];
            ubh.b[2] = dwh[2 * c + 1][0]; ubh.b[3] = dwh[2 * c + 1][1];
            ubl.b[0] = dwl[2 * c][0];     ubl.b[1] = dwl[2 * c][1];
            ubl.b[2] = dwl[2 * c + 1][0]; ubl.b[3] = dwl[2 * c + 1][1];
            acc0h = __builtin_amdgcn_mfma_f32_32x32x16_f16(vf[0][c], ubh.v, acc0h, 0, 0, 0);
            acc0l = __builtin_amdgcn_mfma_f32_32x32x16_f16(vf[0][c], ubl.v, acc0l, 0, 0, 0);
            acc1h = __builtin_amdgcn_mfma_f32_32x32x16_f16(vf[1][c], ubh.v, acc1h, 0, 0, 0);
            acc1l = __builtin_amdgcn_mfma_f32_32x32x16_f16(vf[1][c], ubl.v, acc1l, 0, 0, 0);
        }
        __builtin_amdgcn_s_setprio(0);
    }

    // ---- epilogue step 1: pair-merge m-strips (0,2) and (1,3) --------------
    // scr layout A: idx(wj, et, src, er, l31) stride 33  (33792 B <= 35840)
#define SA(wj_, et_, sr_, er_) ((((((wj_) * 2 + (et_)) * 2 + (sr_)) * 32) + (er_)) * 33)
    __syncthreads();
    if (wi >= 2) {
#pragma unroll
        for (int r = 0; r < 16; ++r) {
            int er = (r & 3) + 8 * (r >> 2) + 4 * hi;
            scr[SA(wj, 0, wi - 2, er) + l31] = acc0h[r];
            scr[SA(wj, 1, wi - 2, er) + l31] = acc1h[r];
        }
    }
    __syncthreads();
    if (wi < 2) {
#pragma unroll
        for (int r = 0; r < 16; ++r) {
            int er = (r & 3) + 8 * (r >> 2) + 4 * hi;
            acc0h[r] += scr[SA(wj, 0, wi, er) + l31];
            acc1h[r] += scr[SA(wj, 1, wi, er) + l31];
        }
    }
    __syncthreads();
    if (wi >= 2) {
#pragma unroll
        for (int r = 0; r < 16; ++r) {
            int er = (r & 3) + 8 * (r >> 2) + 4 * hi;
            scr[SA(wj, 0, wi - 2, er) + l31] = acc0l[r];
            scr[SA(wj, 1, wi - 2, er) + l31] = acc1l[r];
        }
    }
    __syncthreads();
    if (wi < 2) {
#pragma unroll
        for (int r = 0; r < 16; ++r) {
            int er = (r & 3) + 8 * (r >> 2) + 4 * hi;
            acc0l[r] += scr[SA(wj, 0, wi, er) + l31];
            acc1l[r] += scr[SA(wj, 1, wi, er) + l31];
        }
    }
#undef SA

    // ---- epilogue step 2: wi0<->wi1 exchange (original 2-wave reduction) ---
    float zfh[16], zfl[16];
    {
        __syncthreads();
        if (wi < 2) {
#pragma unroll
            for (int r = 0; r < 16; ++r) {
                int er = (r & 3) + 8 * (r >> 2) + 4 * hi;
                float sendh = wi ? acc0h[r] : acc1h[r];
                scr[((wj * 2 + (1 - wi)) * 32 + er) * 33 + l31] = sendh;
            }
        }
        __syncthreads();
        if (wi < 2) {
#pragma unroll
            for (int r = 0; r < 16; ++r) {
                int er = (r & 3) + 8 * (r >> 2) + 4 * hi;
                float keeph = wi ? acc1h[r] : acc0h[r];
                zfh[r] = keeph + scr[((wj * 2 + wi) * 32 + er) * 33 + l31];
            }
        }
        __syncthreads();
        if (wi < 2) {
#pragma unroll
            for (int r = 0; r < 16; ++r) {
                int er = (r & 3) + 8 * (r >> 2) + 4 * hi;
                float sendl = wi ? acc0l[r] : acc1l[r];
                scr[((wj * 2 + (1 - wi)) * 32 + er) * 33 + l31] = sendl;
            }
        }
        __syncthreads();
        if (wi < 2) {
#pragma unroll
            for (int r = 0; r < 16; ++r) {
                int er = (r & 3) + 8 * (r >> 2) + 4 * hi;
                float keepl = wi ? acc1l[r] : acc0l[r];
                zfl[r] = keepl + scr[((wj * 2 + wi) * 32 + er) * 33 + l31];
            }
        }
    }

    // quantize Z (16,8), split digits, store planes. e = 32wi + er (wi<2).
    if (wi < 2) {
        const int b_ = bh / NH, h = bh % NH;
        const int n = qt * 64 + 32 * wj + l31;
        const size_t rowoff = ((size_t)b_ * SEQ + n) * DIM + h * DH;
#pragma unroll
        for (int g = 0; g < 4; ++g) {
            int e0 = 32 * wi + 8 * g + 4 * hi;
            half4 ph, pl;
#pragma unroll
            for (int j = 0; j < 4; ++j) {
                int r = 4 * g + j;
                float zint = fmaf(2048.0f, zfh[r], zfl[r]);  // z_raw*65536
                float zq = rintf(zint * 0.00390625f);
                zq = fminf(fmaxf(zq, -32768.0f), 32767.0f);
                float zdh = rintf(zq * (1.0f / 2048.0f));
                ((_Float16*)&ph)[j] = (_Float16)zdh;
                ((_Float16*)&pl)[j] = (_Float16)(zq - 2048.0f * zdh);
            }
            *(half4*)(Zh16 + rowoff + e0) = ph;
            *(half4*)(Zl16 + rowoff + e0) = pl;
        }
    }
}

// ---------------- K3: output projection, 32x32 MFMA, 64x64 tile -------------
__global__ __launch_bounds__(256, 4) void out_mfma(
    const _Float16* __restrict__ Zh, const _Float16* __restrict__ Zl,
    const _Float16* __restrict__ Wp16, const float* __restrict__ bp16,
    float* __restrict__ O)
{
    __shared__ __align__(16) _Float16 Ah[64 * 64];
    __shared__ __align__(16) _Float16 Al[64 * 64];
    __shared__ __align__(16) _Float16 Bs[64 * 64];
    const int t = threadIdx.x;
    const int w = t >> 6, lane = t & 63;
    const int l31 = lane & 31, hi = lane >> 5;
    const int wr = w >> 1;                // row strip (0/1)
    const int wc = w & 1;                 // col half (0/1)
    const int m0 = blockIdx.y * 64;
    const int col0 = blockIdx.x * 64;

    const int lr = lane >> 3;
    const int lg8 = ((lane & 7) ^ lr) * 8;

    floatx16 acch, accl;
#pragma unroll
    for (int r = 0; r < 16; ++r) { acch[r] = 0.f; accl[r] = 0.f; }

    for (int k0 = 0; k0 < DIM; k0 += 64) {
        __syncthreads();
        GLOAD16(Zh + (size_t)(m0 + 16 * w + lr) * DIM + k0 + lg8,
                &Ah[(2 * w) * 512]);
        GLOAD16(Zh + (size_t)(m0 + 16 * w + 8 + lr) * DIM + k0 + lg8,
                &Ah[(2 * w + 1) * 512]);
        GLOAD16(Zl + (size_t)(m0 + 16 * w + lr) * DIM + k0 + lg8,
                &Al[(2 * w) * 512]);
        GLOAD16(Zl + (size_t)(m0 + 16 * w + 8 + lr) * DIM + k0 + lg8,
                &Al[(2 * w + 1) * 512]);
        GLOAD16(Wp16 + (size_t)(col0 + 16 * w + lr) * DIM + k0 + lg8,
                &Bs[(2 * w) * 512]);
        GLOAD16(Wp16 + (size_t)(col0 + 16 * w + 8 + lr) * DIM + k0 + lg8,
                &Bs[(2 * w + 1) * 512]);
        __syncthreads();
#pragma unroll
        for (int i = 0; i < 4; ++i) {     // k-step of 16
            const int arow = 32 * wr + l31;
            const int brow = 32 * wc + l31;
            const int g = 2 * i + hi;
            half8 ah = *(const half8*)(&Ah[arow * 64 + ((g ^ (arow & 7)) << 3)]);
            half8 al = *(const half8*)(&Al[arow * 64 + ((g ^ (arow & 7)) << 3)]);
            half8 bf = *(const half8*)(&Bs[brow * 64 + ((g ^ (brow & 7)) << 3)]);
            acch = __builtin_amdgcn_mfma_f32_32x32x16_f16(ah, bf, acch, 0, 0, 0);
            accl = __builtin_amdgcn_mfma_f32_32x32x16_f16(al, bf, accl, 0, 0, 0);
        }
    }

    // epilogue: C rows = Z-token-rel er = (r&3)+8*(r>>2)+4*hi, cols = l31.
    {
        const int c = col0 + 32 * wc + l31;
        const float bb = bp16[c];
#pragma unroll
        for (int r = 0; r < 16; ++r) {
            int er = (r & 3) + 8 * (r >> 2) + 4 * hi;
            float y = fmaf(2048.0f, acch[r], accl[r]) + bb;
            float o = rintf(y * 0.00390625f) * 0.00390625f;
            O[(size_t)(m0 + 32 * wr + er) * DIM + c] = o;
        }
    }
}

extern "C" void kernel_launch(void* const* d_in, const int* in_sizes, int n_in,
                              void* d_out, int out_size, void* d_ws, size_t ws_size,
                              hipStream_t stream) {
    const float* q_in = (const float*)d_in[0];
    const float* wqkv = (const float*)d_in[1];
    const float* bqkv = (const float*)d_in[2];
    const float* wp   = (const float*)d_in[3];
    const float* bp   = (const float*)d_in[4];

    char* w = (char*)d_ws;
    _Float16* W16  = (_Float16*)w;  w += (size_t)QKVD * DIM * 2;
    _Float16* Wp16 = (_Float16*)w;  w += (size_t)DIM * DIM * 2;
    float* bq24    = (float*)w;     w += QKVD * 4;
    float* bp16    = (float*)w;     w += DIM * 4;
    _Float16* Xh   = (_Float16*)w;  w += (size_t)NTOK * DIM * 2;
    _Float16* Xl   = (_Float16*)w;  w += (size_t)NTOK * DIM * 2;
    _Float16* Q16  = (_Float16*)w;  w += (size_t)NBH * SEQ * DH * 2;
    _Float16* K16  = (_Float16*)w;  w += (size_t)NBH * SEQ * DH * 2;
    _Float16* Vt16 = (_Float16*)w;  w += (size_t)NBH * SEQ * DH * 2;
    _Float16* Zh16 = (_Float16*)w;  w += (size_t)NTOK * DIM * 2;
    _Float16* Zl16 = (_Float16*)w;  w += (size_t)NTOK * DIM * 2;
    (void)ws_size; (void)in_sizes; (void)n_in; (void)out_size;

    prep<<<dim3(NTOK * DIM / 4 / 256), 256, 0, stream>>>(
        q_in, wqkv, bqkv, wp, bp, Xh, Xl, W16, Wp16, bq24, bp16);
    qkv_mfma<<<dim3(NTOK / 64, QKVD / 128), 256, 0, stream>>>(
        Xh, Xl, W16, bq24, Q16, K16, Vt16);
    attention_mfma<<<dim3(NBH, SEQ / 64), 512, 0, stream>>>(Q16, K16, Vt16, Zh16, Zl16);
    out_mfma<<<dim3(DIM / 64, NTOK / 64), 256, 0, stream>>>(
        Zh16, Zl16, Wp16, bp16, (float*)d_out);
}

// Round 12
// 244.965 us; speedup vs baseline: 4.8894x; 4.8894x over previous
//
#include <hip/hip_runtime.h>

// Quantized MSA, all-MFMA (f16 exact fixed-point digits).
// R15: qkv/out gload_lds + swizzle — WIN (186.4 -> 180.0). R16/17: direct-
//   global attn — REGRESSION. R18: qkv 2-phase — REGRESSION. R19: out 32x32
//   clone — NEUTRAL. R20: qkv 128^2 — REGRESSION (occupancy). R21: qkv 144B
//   rows div-9 — NEUTRAL (kept). R22: out 64x64 — NEUTRAL (kept).
// R23: attention 8 waves x KVBLK=128 — CATASTROPHIC (1075µs) but diagnosed:
//   __launch_bounds__(512,6) demanded 6 waves/SIMD -> 85-VGPR budget ->
//   compiler spilled all 4 accumulators (VGPR_Count=40, 4.4GB scratch
//   traffic, MfmaUtil 1.4%). Occupancy DID hit 41-48% => the TLP structure
//   worked; only the register bound was wrong.
// R24: single fix — launch_bounds(512,4): 128-VGPR budget (fits ~110 need),
//   2 blk/CU x 8 waves = 16 waves/CU (vs R14's grid-capped 12).
//   Everything else byte-identical to R23.

#define NTOK 4096      // B*N
#define DIM  768
#define NH   12
#define DH   64
#define SEQ  2048
#define QKVD 2304      // 3*DIM
#define NBH  24        // B*NH
#define LSTR 72        // f16 LDS row stride: 144 B rows (16B-aligned)
#define KSTR 72        // attention K tile row stride
#define VSTR 136       // attention V^T tile row stride (128 + 8 pad)

typedef _Float16 half8 __attribute__((ext_vector_type(8)));
typedef _Float16 half4 __attribute__((ext_vector_type(4)));
typedef __fp16   fp16x2 __attribute__((ext_vector_type(2)));
typedef float floatx4 __attribute__((ext_vector_type(4)));
typedef float floatx16 __attribute__((ext_vector_type(16)));

// direct global->LDS DMA, 16B/lane; dest = wave-uniform base + lane*16
#define GLOAD16(gsrc, ldst) \
    __builtin_amdgcn_global_load_lds( \
        (const __attribute__((address_space(1))) void*)(gsrc), \
        (__attribute__((address_space(3))) void*)(ldst), 16, 0, 0)

// ---------------- K0: merged prep (X digit split + weight/bias quant) --------
__global__ __launch_bounds__(256) void prep(
    const float* __restrict__ X,
    const float* __restrict__ wqkv, const float* __restrict__ bqkv,
    const float* __restrict__ wp,   const float* __restrict__ bp,
    _Float16* __restrict__ Xh, _Float16* __restrict__ Xl,
    _Float16* __restrict__ W16, _Float16* __restrict__ Wp16,
    float* __restrict__ bq24, float* __restrict__ bp16)
{
    int i = blockIdx.x * 256 + threadIdx.x;
    int i4 = i * 4;
    if (i4 < NTOK * DIM) {           // X (32,16): clamp unreachable for N(0,1)
        float4 x = *(const float4*)(X + i4);
        float xi[4] = {x.x, x.y, x.z, x.w};
        half4 oh, ol;
#pragma unroll
        for (int j = 0; j < 4; ++j) {
            float v = rintf(xi[j] * 65536.0f);
            float h = rintf(v * (1.0f / 2048.0f));
            ((_Float16*)&oh)[j] = (_Float16)h;
            ((_Float16*)&ol)[j] = (_Float16)(v - 2048.0f * h);
        }
        *(half4*)(Xh + i4) = oh;
        *(half4*)(Xl + i4) = ol;
    }
    if (i4 < QKVD * DIM) {           // w*0.05: |w_int| <~ 70, clamp unreachable
        float4 w = *(const float4*)(wqkv + i4);
        half4 o = {(_Float16)rintf(w.x * 256.0f), (_Float16)rintf(w.y * 256.0f),
                   (_Float16)rintf(w.z * 256.0f), (_Float16)rintf(w.w * 256.0f)};
        *(half4*)(W16 + i4) = o;
    }
    if (i4 < DIM * DIM) {
        float4 w = *(const float4*)(wp + i4);
        half4 o = {(_Float16)rintf(w.x * 256.0f), (_Float16)rintf(w.y * 256.0f),
                   (_Float16)rintf(w.z * 256.0f), (_Float16)rintf(w.w * 256.0f)};
        *(half4*)(Wp16 + i4) = o;
    }
    if (i < QKVD) bq24[i] = rintf(bqkv[i] * 256.0f) * 65536.0f;  // int24 units
    if (i < DIM)  bp16[i] = rintf(bp[i] * 256.0f) * 256.0f;      // int16 units
}

// ---------------- K1: QKV projection, 32x32 MFMA, 64x128 tile, 4 blk/CU ------
// 144B LDS rows + gload_lds staging via div-9 slot mapping; conflict-free reads.
__global__ __launch_bounds__(256, 4) void qkv_mfma(
    const _Float16* __restrict__ Xh, const _Float16* __restrict__ Xl,
    const _Float16* __restrict__ W16, const float* __restrict__ bq24,
    _Float16* __restrict__ Q16, _Float16* __restrict__ K16,
    _Float16* __restrict__ Vt16)
{
    __shared__ __align__(16) _Float16 Ah[64 * LSTR];    //  9216 B
    __shared__ __align__(16) _Float16 Al[64 * LSTR];    //  9216 B
    __shared__ __align__(16) _Float16 Bs[128 * LSTR];   // 18432 B
    const int t = threadIdx.x;
    const int w = t >> 6, lane = t & 63;
    const int l31 = lane & 31, hi = lane >> 5;
    const int wr = w >> 1;                // row strip (0/1)
    const int wc = w & 1;                 // col half (0/1)
    const int m0 = blockIdx.x * 64;       // token rows (x-fastest: XCD = x%8)
    const int col0 = blockIdx.y * 128;    // output cols

    // staging: wave p stages plane p. Slot s = 64j + lane covers LDS bytes
    // s*16; row = s/9, slot-in-row = s%9 (9th slot = 8-half pad, refetch g0).
    const _Float16* gsrc0 = (w == 0) ? Xh + (size_t)m0 * DIM
                          : (w == 1) ? Xl + (size_t)m0 * DIM
                          : W16 + (size_t)(col0 + ((w == 3) ? 64 : 0)) * DIM;
    _Float16* ldst0 = (w == 0) ? Ah : (w == 1) ? Al
                      : Bs + ((w == 3) ? 64 * LSTR : 0);
    int goff[9];                          // per-lane source elem offsets
#pragma unroll
    for (int j = 0; j < 9; ++j) {
        int s = 64 * j + lane;            // 0..575
        int row = (s * 7282) >> 16;       // exact s/9 for s < 32768
        int sl = s - 9 * row;             // 0..8
        goff[j] = row * DIM + ((sl & 7) * 8);   // sl==8 -> granule 0 (pad)
    }

    floatx16 acch[2], accl[2];            // [ct] -- constant indices after unroll
#pragma unroll
    for (int ct = 0; ct < 2; ++ct)
#pragma unroll
        for (int r = 0; r < 16; ++r) { acch[ct][r] = 0.f; accl[ct][r] = 0.f; }

    for (int k0 = 0; k0 < DIM; k0 += 64) {
        __syncthreads();
#pragma unroll
        for (int j = 0; j < 9; ++j)
            GLOAD16(gsrc0 + k0 + goff[j], ldst0 + j * 512);
        __syncthreads();
#pragma unroll
        for (int i = 0; i < 4; ++i) {     // k-step of 16
            const int arow = 32 * wr + l31;
            half8 ah = *(const half8*)(&Ah[arow * LSTR + 16 * i + 8 * hi]);
            half8 al = *(const half8*)(&Al[arow * LSTR + 16 * i + 8 * hi]);
#pragma unroll
            for (int ct = 0; ct < 2; ++ct) {
                const int brow = 64 * wc + 32 * ct + l31;
                half8 bf = *(const half8*)(&Bs[brow * LSTR + 16 * i + 8 * hi]);
                acch[ct] = __builtin_amdgcn_mfma_f32_32x32x16_f16(ah, bf, acch[ct], 0, 0, 0);
                accl[ct] = __builtin_amdgcn_mfma_f32_32x32x16_f16(al, bf, accl[ct], 0, 0, 0);
            }
        }
    }

    // epilogue: C rows = token-rel er = (r&3)+8*(r>>2)+4*hi, cols = c-rel l31.
    const int b_ = m0 >> 11;
    const int nbase = (m0 & 2047) + 32 * wr;
#pragma unroll
    for (int ct = 0; ct < 2; ++ct) {
        const int c = col0 + 64 * wc + 32 * ct + l31;
        const int h = c / 192;
        const int jj = c % 192;
        const int kind = jj >> 6;         // 0=Q, 1=K, 2=V (uniform per ct-tile)
        const int e = jj & 63;
        const int bh = b_ * NH + h;
        const float bb = bq24[c];
        float qv[16];
#pragma unroll
        for (int r = 0; r < 16; ++r) {
            float y = fmaf(2048.0f, acch[ct][r], accl[ct][r]) + bb;
            float q = rintf(y * (1.0f / 65536.0f));
            qv[r] = fminf(fmaxf(q, -32768.0f), 32767.0f);
        }
        if (kind == 2) {
            // sigma (swap bit2<->bit3 within 16-block): er = 8g'+4hi+j maps to
            // 16*(g>>1) + 8*hi + 4*(g&1) + j -- j consecutive -> half4 stores.
#pragma unroll
            for (int g = 0; g < 4; ++g) {
                int nv = nbase + 16 * (g >> 1) + 8 * hi + 4 * (g & 1);
                half4 o = {(_Float16)qv[4 * g + 0], (_Float16)qv[4 * g + 1],
                           (_Float16)qv[4 * g + 2], (_Float16)qv[4 * g + 3]};
                *(half4*)(Vt16 + ((size_t)bh * DH + e) * SEQ + nv) = o;
            }
        } else {
            _Float16* dst = (kind == 0) ? Q16 : K16;
#pragma unroll
            for (int r = 0; r < 16; ++r) {
                int er = (r & 3) + 8 * (r >> 2) + 4 * hi;
                dst[((size_t)bh * SEQ + nbase + er) * DH + e] = (_Float16)qv[r];
            }
        }
    }
}

// ---------------- K2: attention, 32x32 MFMA, 8 waves x KVBLK=128 ------------
// 4 m-strips (wi) x 2 q-halves (wj); 16 iters; single-buffered K/V staging.
// launch_bounds(512,4): 128-VGPR budget (R23's (512,6) forced acc spills).
__global__ __launch_bounds__(512, 4) void attention_mfma(
    const _Float16* __restrict__ Q16, const _Float16* __restrict__ K16,
    const _Float16* __restrict__ Vt16,
    _Float16* __restrict__ Zh16, _Float16* __restrict__ Zl16)
{
    // Ks[128][72] (18432 B) + Vs[64][136] (17408 B) = 35840 B.
    // Epilogue scratch overlays: pair-merge 33792 B, exchange 16896 B.
    __shared__ __align__(16) char smem[128 * KSTR * 2 + 64 * VSTR * 2];
    _Float16* Ks = (_Float16*)smem;
    _Float16* Vs = Ks + 128 * KSTR;
    float* scr = (float*)smem;

    const int t = threadIdx.x;
    const int bh = blockIdx.x;
    const int qt = blockIdx.y;
    const int w = t >> 6, lane = t & 63;
    const int l31 = lane & 31, hi = lane >> 5;
    const int wj = w & 1;        // q-half
    const int wi = w >> 1;       // m-strip 0..3
    const _Float16* Qg = Q16 + ((size_t)bh * SEQ + qt * 64) * DH;
    const _Float16* Kg = K16 + (size_t)bh * SEQ * DH;
    const _Float16* Vg = Vt16 + (size_t)bh * DH * SEQ;

    // staging slots: 512 threads x 2 slots cover K(128x8 gran) + V(64x16 gran)
    const int sB = t + 512;
    const int kr0 = t >> 3,  kk0 = t & 7;
    const int kr1 = sB >> 3, kk1 = sB & 7;
    const int vr0 = t >> 4,  vm0 = t & 15;
    const int vr1 = sB >> 4, vm1 = sB & 15;

    // Q B-frags (whole kernel): B[n=q=l31][k_e = 16i + 8hi + j]
    half8 qf[4];
#pragma unroll
    for (int i = 0; i < 4; ++i)
        qf[i] = *(const half8*)(Qg + (32 * wj + l31) * DH + 16 * i + 8 * hi);

    // prologue: load tile 0 into regs
    half8 pk0 = *(const half8*)(Kg + (size_t)kr0 * DH + kk0 * 8);
    half8 pk1 = *(const half8*)(Kg + (size_t)kr1 * DH + kk1 * 8);
    half8 pv0 = *(const half8*)(Vg + (size_t)vr0 * SEQ + vm0 * 8);
    half8 pv1 = *(const half8*)(Vg + (size_t)vr1 * SEQ + vm1 * 8);

    floatx16 acc0h, acc0l, acc1h, acc1l;   // [et=0/1][digit h/l]
#pragma unroll
    for (int r = 0; r < 16; ++r) { acc0h[r] = 0.f; acc0l[r] = 0.f; acc1h[r] = 0.f; acc1l[r] = 0.f; }

    for (int it = 0; it < 16; ++it) {
        __syncthreads();                   // prior tile's reads complete
        *(half8*)(&Ks[kr0 * KSTR + kk0 * 8]) = pk0;
        *(half8*)(&Ks[kr1 * KSTR + kk1 * 8]) = pk1;
        *(half8*)(&Vs[vr0 * VSTR + vm0 * 8]) = pv0;
        *(half8*)(&Vs[vr1 * VSTR + vm1 * 8]) = pv1;
        __syncthreads();                   // writes visible

        // T14: issue next tile's loads; latency hides under this tile's compute
        if (it < 15) {
            const int mn = (it + 1) * 128;
            pk0 = *(const half8*)(Kg + (size_t)(mn + kr0) * DH + kk0 * 8);
            pk1 = *(const half8*)(Kg + (size_t)(mn + kr1) * DH + kk1 * 8);
            pv0 = *(const half8*)(Vg + (size_t)vr0 * SEQ + mn + vm0 * 8);
            pv1 = *(const half8*)(Vg + (size_t)vr1 * SEQ + mn + vm1 * 8);
        }

        // phase 1: S strip = K(strip wi) . Q^T ; sacc = S_raw * 65536
        floatx16 sc;
#pragma unroll
        for (int r = 0; r < 16; ++r) sc[r] = 0.f;
        __builtin_amdgcn_s_setprio(1);
#pragma unroll
        for (int i = 0; i < 4; ++i) {
            half8 kf = *(const half8*)(&Ks[(32 * wi + l31) * KSTR + 16 * i + 8 * hi]);
            sc = __builtin_amdgcn_mfma_f32_32x32x16_f16(kf, qf[i], sc, 0, 0, 0);
        }
        __builtin_amdgcn_s_setprio(0);

        // quantize (16,8) + digit split in registers
        float hh[16], ll[16];
#pragma unroll
        for (int r = 0; r < 16; ++r) {
            float v = rintf(sc[r] * 0.00390625f);
            v = fminf(fmaxf(v, -32768.0f), 32767.0f);
            float h = rintf(v * (1.0f / 2048.0f));
            hh[r] = h;
            ll[r] = fmaf(-2048.0f, h, v);
        }
        int dwh[4][2], dwl[4][2];
        union { fp16x2 h; int i; } cv;
#pragma unroll
        for (int g = 0; g < 4; ++g) {
            cv.h = __builtin_amdgcn_cvt_pkrtz(hh[4 * g + 0], hh[4 * g + 1]); dwh[g][0] = cv.i;
            cv.h = __builtin_amdgcn_cvt_pkrtz(hh[4 * g + 2], hh[4 * g + 3]); dwh[g][1] = cv.i;
            cv.h = __builtin_amdgcn_cvt_pkrtz(ll[4 * g + 0], ll[4 * g + 1]); dwl[g][0] = cv.i;
            cv.h = __builtin_amdgcn_cvt_pkrtz(ll[4 * g + 2], ll[4 * g + 3]); dwl[g][1] = cv.i;
        }

        // phase 2: A = V^T rows (sigma-ordered cols of strip wi), B = local S.
        half8 vf[2][2];
#pragma unroll
        for (int et = 0; et < 2; ++et)
#pragma unroll
            for (int c = 0; c < 2; ++c)
                vf[et][c] = *(const half8*)(&Vs[(32 * et + l31) * VSTR + 32 * wi + 16 * c + 8 * hi]);
        __builtin_amdgcn_s_setprio(1);
#pragma unroll
        for (int c = 0; c < 2; ++c) {
            union { int b[4]; half8 v; } ubh, ubl;
            ubh.b[0] = dwh[2 * c][0];     ubh.b[1] = dwh[2 * c][1];
            ubh.b[2] = dwh[2 * c + 1][0]; ubh.b[3] = dwh[2 * c + 1][1];
            ubl.b[0] = dwl[2 * c][0];     ubl.b[1] = dwl[2 * c][1];
            ubl.b[2] = dwl[2 * c + 1][0]; ubl.b[3] = dwl[2 * c + 1][1];
            acc0h = __builtin_amdgcn_mfma_f32_32x32x16_f16(vf[0][c], ubh.v, acc0h, 0, 0, 0);
            acc0l = __builtin_amdgcn_mfma_f32_32x32x16_f16(vf[0][c], ubl.v, acc0l, 0, 0, 0);
            acc1h = __builtin_amdgcn_mfma_f32_32x32x16_f16(vf[1][c], ubh.v, acc1h, 0, 0, 0);
            acc1l = __builtin_amdgcn_mfma_f32_32x32x16_f16(vf[1][c], ubl.v, acc1l, 0, 0, 0);
        }
        __builtin_amdgcn_s_setprio(0);
    }

    // ---- epilogue step 1: pair-merge m-strips (0,2) and (1,3) --------------
    // scr layout A: idx(wj, et, src, er, l31) stride 33  (33792 B <= 35840)
#define SA(wj_, et_, sr_, er_) ((((((wj_) * 2 + (et_)) * 2 + (sr_)) * 32) + (er_)) * 33)
    __syncthreads();
    if (wi >= 2) {
#pragma unroll
        for (int r = 0; r < 16; ++r) {
            int er = (r & 3) + 8 * (r >> 2) + 4 * hi;
            scr[SA(wj, 0, wi - 2, er) + l31] = acc0h[r];
            scr[SA(wj, 1, wi - 2, er) + l31] = acc1h[r];
        }
    }
    __syncthreads();
    if (wi < 2) {
#pragma unroll
        for (int r = 0; r < 16; ++r) {
            int er = (r & 3) + 8 * (r >> 2) + 4 * hi;
            acc0h[r] += scr[SA(wj, 0, wi, er) + l31];
            acc1h[r] += scr[SA(wj, 1, wi, er) + l31];
        }
    }
    __syncthreads();
    if (wi >= 2) {
#pragma unroll
        for (int r = 0; r < 16; ++r) {
            int er = (r & 3) + 8 * (r >> 2) + 4 * hi;
            scr[SA(wj, 0, wi - 2, er) + l31] = acc0l[r];
            scr[SA(wj, 1, wi - 2, er) + l31] = acc1l[r];
        }
    }
    __syncthreads();
    if (wi < 2) {
#pragma unroll
        for (int r = 0; r < 16; ++r) {
            int er = (r & 3) + 8 * (r >> 2) + 4 * hi;
            acc0l[r] += scr[SA(wj, 0, wi, er) + l31];
            acc1l[r] += scr[SA(wj, 1, wi, er) + l31];
        }
    }
#undef SA

    // ---- epilogue step 2: wi0<->wi1 exchange (original 2-wave reduction) ---
    float zfh[16], zfl[16];
    {
        __syncthreads();
        if (wi < 2) {
#pragma unroll
            for (int r = 0; r < 16; ++r) {
                int er = (r & 3) + 8 * (r >> 2) + 4 * hi;
                float sendh = wi ? acc0h[r] : acc1h[r];
                scr[((wj * 2 + (1 - wi)) * 32 + er) * 33 + l31] = sendh;
            }
        }
        __syncthreads();
        if (wi < 2) {
#pragma unroll
            for (int r = 0; r < 16; ++r) {
                int er = (r & 3) + 8 * (r >> 2) + 4 * hi;
                float keeph = wi ? acc1h[r] : acc0h[r];
                zfh[r] = keeph + scr[((wj * 2 + wi) * 32 + er) * 33 + l31];
            }
        }
        __syncthreads();
        if (wi < 2) {
#pragma unroll
            for (int r = 0; r < 16; ++r) {
                int er = (r & 3) + 8 * (r >> 2) + 4 * hi;
                float sendl = wi ? acc0l[r] : acc1l[r];
                scr[((wj * 2 + (1 - wi)) * 32 + er) * 33 + l31] = sendl;
            }
        }
        __syncthreads();
        if (wi < 2) {
#pragma unroll
            for (int r = 0; r < 16; ++r) {
                int er = (r & 3) + 8 * (r >> 2) + 4 * hi;
                float keepl = wi ? acc1l[r] : acc0l[r];
                zfl[r] = keepl + scr[((wj * 2 + wi) * 32 + er) * 33 + l31];
            }
        }
    }

    // quantize Z (16,8), split digits, store planes. e = 32wi + er (wi<2).
    if (wi < 2) {
        const int b_ = bh / NH, h = bh % NH;
        const int n = qt * 64 + 32 * wj + l31;
        const size_t rowoff = ((size_t)b_ * SEQ + n) * DIM + h * DH;
#pragma unroll
        for (int g = 0; g < 4; ++g) {
            int e0 = 32 * wi + 8 * g + 4 * hi;
            half4 ph, pl;
#pragma unroll
            for (int j = 0; j < 4; ++j) {
                int r = 4 * g + j;
                float zint = fmaf(2048.0f, zfh[r], zfl[r]);  // z_raw*65536
                float zq = rintf(zint * 0.00390625f);
                zq = fminf(fmaxf(zq, -32768.0f), 32767.0f);
                float zdh = rintf(zq * (1.0f / 2048.0f));
                ((_Float16*)&ph)[j] = (_Float16)zdh;
                ((_Float16*)&pl)[j] = (_Float16)(zq - 2048.0f * zdh);
            }
            *(half4*)(Zh16 + rowoff + e0) = ph;
            *(half4*)(Zl16 + rowoff + e0) = pl;
        }
    }
}

// ---------------- K3: output projection, 32x32 MFMA, 64x64 tile -------------
__global__ __launch_bounds__(256, 4) void out_mfma(
    const _Float16* __restrict__ Zh, const _Float16* __restrict__ Zl,
    const _Float16* __restrict__ Wp16, const float* __restrict__ bp16,
    float* __restrict__ O)
{
    __shared__ __align__(16) _Float16 Ah[64 * 64];
    __shared__ __align__(16) _Float16 Al[64 * 64];
    __shared__ __align__(16) _Float16 Bs[64 * 64];
    const int t = threadIdx.x;
    const int w = t >> 6, lane = t & 63;
    const int l31 = lane & 31, hi = lane >> 5;
    const int wr = w >> 1;                // row strip (0/1)
    const int wc = w & 1;                 // col half (0/1)
    const int m0 = blockIdx.y * 64;
    const int col0 = blockIdx.x * 64;

    const int lr = lane >> 3;
    const int lg8 = ((lane & 7) ^ lr) * 8;

    floatx16 acch, accl;
#pragma unroll
    for (int r = 0; r < 16; ++r) { acch[r] = 0.f; accl[r] = 0.f; }

    for (int k0 = 0; k0 < DIM; k0 += 64) {
        __syncthreads();
        GLOAD16(Zh + (size_t)(m0 + 16 * w + lr) * DIM + k0 + lg8,
                &Ah[(2 * w) * 512]);
        GLOAD16(Zh + (size_t)(m0 + 16 * w + 8 + lr) * DIM + k0 + lg8,
                &Ah[(2 * w + 1) * 512]);
        GLOAD16(Zl + (size_t)(m0 + 16 * w + lr) * DIM + k0 + lg8,
                &Al[(2 * w) * 512]);
        GLOAD16(Zl + (size_t)(m0 + 16 * w + 8 + lr) * DIM + k0 + lg8,
                &Al[(2 * w + 1) * 512]);
        GLOAD16(Wp16 + (size_t)(col0 + 16 * w + lr) * DIM + k0 + lg8,
                &Bs[(2 * w) * 512]);
        GLOAD16(Wp16 + (size_t)(col0 + 16 * w + 8 + lr) * DIM + k0 + lg8,
                &Bs[(2 * w + 1) * 512]);
        __syncthreads();
#pragma unroll
        for (int i = 0; i < 4; ++i) {     // k-step of 16
            const int arow = 32 * wr + l31;
            const int brow = 32 * wc + l31;
            const int g = 2 * i + hi;
            half8 ah = *(const half8*)(&Ah[arow * 64 + ((g ^ (arow & 7)) << 3)]);
            half8 al = *(const half8*)(&Al[arow * 64 + ((g ^ (arow & 7)) << 3)]);
            half8 bf = *(const half8*)(&Bs[brow * 64 + ((g ^ (brow & 7)) << 3)]);
            acch = __builtin_amdgcn_mfma_f32_32x32x16_f16(ah, bf, acch, 0, 0, 0);
            accl = __builtin_amdgcn_mfma_f32_32x32x16_f16(al, bf, accl, 0, 0, 0);
        }
    }

    // epilogue: C rows = Z-token-rel er = (r&3)+8*(r>>2)+4*hi, cols = l31.
    {
        const int c = col0 + 32 * wc + l31;
        const float bb = bp16[c];
#pragma unroll
        for (int r = 0; r < 16; ++r) {
            int er = (r & 3) + 8 * (r >> 2) + 4 * hi;
            float y = fmaf(2048.0f, acch[r], accl[r]) + bb;
            float o = rintf(y * 0.00390625f) * 0.00390625f;
            O[(size_t)(m0 + 32 * wr + er) * DIM + c] = o;
        }
    }
}

extern "C" void kernel_launch(void* const* d_in, const int* in_sizes, int n_in,
                              void* d_out, int out_size, void* d_ws, size_t ws_size,
                              hipStream_t stream) {
    const float* q_in = (const float*)d_in[0];
    const float* wqkv = (const float*)d_in[1];
    const float* bqkv = (const float*)d_in[2];
    const float* wp   = (const float*)d_in[3];
    const float* bp   = (const float*)d_in[4];

    char* w = (char*)d_ws;
    _Float16* W16  = (_Float16*)w;  w += (size_t)QKVD * DIM * 2;
    _Float16* Wp16 = (_Float16*)w;  w += (size_t)DIM * DIM * 2;
    float* bq24    = (float*)w;     w += QKVD * 4;
    float* bp16    = (float*)w;     w += DIM * 4;
    _Float16* Xh   = (_Float16*)w;  w += (size_t)NTOK * DIM * 2;
    _Float16* Xl   = (_Float16*)w;  w += (size_t)NTOK * DIM * 2;
    _Float16* Q16  = (_Float16*)w;  w += (size_t)NBH * SEQ * DH * 2;
    _Float16* K16  = (_Float16*)w;  w += (size_t)NBH * SEQ * DH * 2;
    _Float16* Vt16 = (_Float16*)w;  w += (size_t)NBH * SEQ * DH * 2;
    _Float16* Zh16 = (_Float16*)w;  w += (size_t)NTOK * DIM * 2;
    _Float16* Zl16 = (_Float16*)w;  w += (size_t)NTOK * DIM * 2;
    (void)ws_size; (void)in_sizes; (void)n_in; (void)out_size;

    prep<<<dim3(NTOK * DIM / 4 / 256), 256, 0, stream>>>(
        q_in, wqkv, bqkv, wp, bp, Xh, Xl, W16, Wp16, bq24, bp16);
    qkv_mfma<<<dim3(NTOK / 64, QKVD / 128), 256, 0, stream>>>(
        Xh, Xl, W16, bq24, Q16, K16, Vt16);
    attention_mfma<<<dim3(NBH, SEQ / 64), 512, 0, stream>>>(Q16, K16, Vt16, Zh16, Zl16);
    out_mfma<<<dim3(DIM / 64, NTOK / 64), 256, 0, stream>>>(
        Zh16, Zl16, Wp16, bp16, (float*)d_out);
}